// Round 1
// baseline (2948.436 us; speedup 1.0000x reference)
//
#include <hip/hip_runtime.h>

#define NN 50000
#define NE 800000
#define C_IN 384
#define C_HID 128

// ---------------- degree / dinv ----------------
__global__ __launch_bounds__(256) void k_deg(const int* __restrict__ dst,
                                             float* __restrict__ deg) {
    int i = blockIdx.x * 256 + threadIdx.x;
    if (i < NE) atomicAdd(&deg[dst[i]], 1.0f);
}

__global__ __launch_bounds__(256) void k_dinv(const float* __restrict__ deg,
                                              float* __restrict__ dinv) {
    int i = blockIdx.x * 256 + threadIdx.x;
    if (i < NN) dinv[i] = rsqrtf(deg[i] + 1.0f);  // +1 = self loop
}

// ---------------- fp32 tiled GEMM ----------------
// h = f(X) @ W,  f = (IN_RELU_BIAS ? relu(x + bin[k]) : x)
// out_main[r,c] = h[r,c]
// out_self[r,c] = h[r,c]*dinv[r]^2 + (OUT_BIAS ? bout[c] : 0)   (self-loop init)
template <bool IN_RELU_BIAS, bool OUT_BIAS>
__global__ __launch_bounds__(256) void k_gemm(const float* __restrict__ X,
                                              const float* __restrict__ W,
                                              const float* __restrict__ bin,
                                              const float* __restrict__ bout,
                                              const float* __restrict__ dinv,
                                              float* __restrict__ out_main,
                                              float* __restrict__ out_self,
                                              int K) {
    constexpr int BM = 64, BN = 128, BK = 16;
    __shared__ float As[BK][68];   // transposed [k][m], padded 64->68
    __shared__ float Bs[BK][BN];

    const int tid = threadIdx.x;
    const int bm  = blockIdx.x * BM;
    const int ty  = tid >> 4;     // 0..15 -> rows ty*4 .. ty*4+3
    const int tx  = tid & 15;     // 0..15 -> cols tx*8 .. tx*8+7

    float acc[4][8];
#pragma unroll
    for (int i = 0; i < 4; ++i)
#pragma unroll
        for (int j = 0; j < 8; ++j) acc[i][j] = 0.f;

    // A-tile load coords: one float4 per thread per tile
    const int lrow = tid >> 2;          // 0..63
    const int lk4  = (tid & 3) * 4;     // 0,4,8,12
    int grow = bm + lrow;
    if (grow >= NN) grow = NN - 1;      // clamp (stores are guarded)
    const float* xrow = X + (size_t)grow * K;

    // B-tile load coords: two float4 per thread per tile
    const int br = tid >> 5;            // 0..7
    const int bc = (tid & 31) * 4;      // 0..124

    for (int k0 = 0; k0 < K; k0 += BK) {
        float4 a = *(const float4*)(xrow + k0 + lk4);
        if (IN_RELU_BIAS) {
            float4 bb = *(const float4*)(bin + k0 + lk4);
            a.x = fmaxf(a.x + bb.x, 0.f);
            a.y = fmaxf(a.y + bb.y, 0.f);
            a.z = fmaxf(a.z + bb.z, 0.f);
            a.w = fmaxf(a.w + bb.w, 0.f);
        }
        As[lk4 + 0][lrow] = a.x;
        As[lk4 + 1][lrow] = a.y;
        As[lk4 + 2][lrow] = a.z;
        As[lk4 + 3][lrow] = a.w;

        *(float4*)&Bs[br][bc]     = *(const float4*)(W + (size_t)(k0 + br) * BN + bc);
        *(float4*)&Bs[br + 8][bc] = *(const float4*)(W + (size_t)(k0 + br + 8) * BN + bc);

        __syncthreads();
#pragma unroll
        for (int kk = 0; kk < BK; ++kk) {
            const float4 av  = *(const float4*)&As[kk][ty * 4];
            const float4 b0  = *(const float4*)&Bs[kk][tx * 8];
            const float4 b1v = *(const float4*)&Bs[kk][tx * 8 + 4];
            const float aa[4] = {av.x, av.y, av.z, av.w};
            const float bb[8] = {b0.x, b0.y, b0.z, b0.w, b1v.x, b1v.y, b1v.z, b1v.w};
#pragma unroll
            for (int i = 0; i < 4; ++i)
#pragma unroll
                for (int j = 0; j < 8; ++j)
                    acc[i][j] = fmaf(aa[i], bb[j], acc[i][j]);
        }
        __syncthreads();
    }

    // epilogue
#pragma unroll
    for (int i = 0; i < 4; ++i) {
        const int r = bm + ty * 4 + i;
        if (r < NN) {
            const float dv = dinv[r];
            const float d2 = dv * dv;
            float* om = out_main + (size_t)r * BN + tx * 8;
            float* os = out_self + (size_t)r * BN + tx * 8;
#pragma unroll
            for (int j = 0; j < 8; j += 4) {
                float4 v = make_float4(acc[i][j], acc[i][j + 1], acc[i][j + 2], acc[i][j + 3]);
                *(float4*)(om + j) = v;
                float4 s;
                s.x = v.x * d2 + (OUT_BIAS ? bout[tx * 8 + j + 0] : 0.f);
                s.y = v.y * d2 + (OUT_BIAS ? bout[tx * 8 + j + 1] : 0.f);
                s.z = v.z * d2 + (OUT_BIAS ? bout[tx * 8 + j + 2] : 0.f);
                s.w = v.w * d2 + (OUT_BIAS ? bout[tx * 8 + j + 3] : 0.f);
                *(float4*)(os + j) = s;
            }
        }
    }
}

// ---------------- edge scatter (atomic) ----------------
// out[dst] += h[src] * dinv[src]*dinv[dst];  32 lanes per edge, 4 ch each
__global__ __launch_bounds__(256) void k_scatter(const float* __restrict__ h,
                                                 const int* __restrict__ src,
                                                 const int* __restrict__ dst,
                                                 const float* __restrict__ dinv,
                                                 float* __restrict__ out) {
    const int t = blockIdx.x * 256 + threadIdx.x;
    const int e = t >> 5;
    if (e >= NE) return;
    const int c = (t & 31) << 2;
    const int s = src[e];
    const int d = dst[e];
    const float norm = dinv[s] * dinv[d];
    const float4 v = *(const float4*)(h + (size_t)s * C_HID + c);
    float* o = out + (size_t)d * C_HID + c;
    atomicAdd(o + 0, v.x * norm);
    atomicAdd(o + 1, v.y * norm);
    atomicAdd(o + 2, v.z * norm);
    atomicAdd(o + 3, v.w * norm);
}

extern "C" void kernel_launch(void* const* d_in, const int* in_sizes, int n_in,
                              void* d_out, int out_size, void* d_ws, size_t ws_size,
                              hipStream_t stream) {
    const float* x  = (const float*)d_in[0];
    const int*   ei = (const int*)d_in[1];
    const float* W1 = (const float*)d_in[2];
    const float* b1 = (const float*)d_in[3];
    const float* W2 = (const float*)d_in[4];
    const float* b2 = (const float*)d_in[5];
    float* out = (float*)d_out;

    const int* src = ei;
    const int* dst = ei + NE;

    float* deg  = (float*)d_ws;                       // NN floats
    float* dinv = deg + 50048;                        // NN floats
    float* A    = dinv + 50048;                       // NN*128  (h buffer)
    float* B    = A + (size_t)NN * C_HID;             // NN*128  (agg buffer)

    hipMemsetAsync(deg, 0, NN * sizeof(float), stream);
    k_deg<<<(NE + 255) / 256, 256, 0, stream>>>(dst, deg);
    k_dinv<<<(NN + 255) / 256, 256, 0, stream>>>(deg, dinv);

    const int gblocks = (NN + 63) / 64;
    // layer 1: h1 = x@W1 -> A ;  B = h1*dinv^2 (self loop term)
    k_gemm<false, false><<<gblocks, 256, 0, stream>>>(x, W1, nullptr, nullptr, dinv, A, B, C_IN);
    // B += scatter(h1)
    k_scatter<<<(NE * 32) / 256, 256, 0, stream>>>(A, src, dst, dinv, B);
    // layer 2: h2 = relu(B + b1)@W2 -> A ; out = h2*dinv^2 + b2
    k_gemm<true, true><<<gblocks, 256, 0, stream>>>(B, W2, b1, b2, dinv, A, out, C_HID);
    // out += scatter(h2)
    k_scatter<<<(NE * 32) / 256, 256, 0, stream>>>(A, src, dst, dinv, out);
}

// Round 2
// 553.424 us; speedup vs baseline: 5.3276x; 5.3276x over previous
//
#include <hip/hip_runtime.h>

#define NN 50000
#define NE 800000
#define C_IN 384
#define C_HID 128

// ---------------- degree count (int) ----------------
__global__ __launch_bounds__(256) void k_deg(const int* __restrict__ dst,
                                             int* __restrict__ cnt) {
    int i = blockIdx.x * 256 + threadIdx.x;
    if (i < NE) atomicAdd(&cnt[dst[i]], 1);
}

__global__ __launch_bounds__(256) void k_dinv(const int* __restrict__ cnt,
                                              float* __restrict__ dinv) {
    int i = blockIdx.x * 256 + threadIdx.x;
    if (i < NN) dinv[i] = rsqrtf((float)cnt[i] + 1.0f);  // +1 = self loop
}

// ---------------- single-block exclusive scan over NN counts ----------------
__global__ __launch_bounds__(1024) void k_scan(const int* __restrict__ cnt,
                                               int* __restrict__ rowptr,
                                               int* __restrict__ cursor) {
    __shared__ int part[1024];
    const int t = threadIdx.x;
    const int CH = (NN + 1023) / 1024;  // 49
    const int lo = t * CH;
    const int hi = (lo + CH < NN) ? lo + CH : NN;
    int s = 0;
    for (int i = lo; i < hi; ++i) s += cnt[i];
    part[t] = s;
    __syncthreads();
    for (int off = 1; off < 1024; off <<= 1) {
        int v = (t >= off) ? part[t - off] : 0;
        __syncthreads();
        part[t] += v;
        __syncthreads();
    }
    int run = (t == 0) ? 0 : part[t - 1];
    for (int i = lo; i < hi; ++i) {
        rowptr[i] = run;
        cursor[i] = run;
        run += cnt[i];
    }
    if (t == 1023) rowptr[NN] = run;
}

// ---------------- CSR fill ----------------
__global__ __launch_bounds__(256) void k_fill(const int* __restrict__ src,
                                              const int* __restrict__ dst,
                                              int* __restrict__ cursor,
                                              int* __restrict__ csr_src) {
    int e = blockIdx.x * 256 + threadIdx.x;
    if (e < NE) {
        int p = atomicAdd(&cursor[dst[e]], 1);
        csr_src[p] = src[e];
    }
}

// ---------------- fp32 tiled GEMM ----------------
// h = f(X) @ W,  f = (IN_RELU_BIAS ? relu(x + bin[k]) : x)
// out_main[r,c] = h[r,c]
// out_self[r,c] = h[r,c]*dinv[r]^2 + (OUT_BIAS ? bout[c] : 0)   (self-loop init)
template <bool IN_RELU_BIAS, bool OUT_BIAS>
__global__ __launch_bounds__(256) void k_gemm(const float* __restrict__ X,
                                              const float* __restrict__ W,
                                              const float* __restrict__ bin,
                                              const float* __restrict__ bout,
                                              const float* __restrict__ dinv,
                                              float* __restrict__ out_main,
                                              float* __restrict__ out_self,
                                              int K) {
    constexpr int BM = 64, BN = 128, BK = 16;
    __shared__ float As[BK][68];   // transposed [k][m], padded 64->68
    __shared__ float Bs[BK][BN];

    const int tid = threadIdx.x;
    const int bm  = blockIdx.x * BM;
    const int ty  = tid >> 4;     // 0..15 -> rows ty*4 .. ty*4+3
    const int tx  = tid & 15;     // 0..15 -> cols tx*8 .. tx*8+7

    float acc[4][8];
#pragma unroll
    for (int i = 0; i < 4; ++i)
#pragma unroll
        for (int j = 0; j < 8; ++j) acc[i][j] = 0.f;

    const int lrow = tid >> 2;          // 0..63
    const int lk4  = (tid & 3) * 4;     // 0,4,8,12
    int grow = bm + lrow;
    if (grow >= NN) grow = NN - 1;      // clamp (stores are guarded)
    const float* xrow = X + (size_t)grow * K;

    const int br = tid >> 5;            // 0..7
    const int bc = (tid & 31) * 4;      // 0..124

    for (int k0 = 0; k0 < K; k0 += BK) {
        float4 a = *(const float4*)(xrow + k0 + lk4);
        if (IN_RELU_BIAS) {
            float4 bb = *(const float4*)(bin + k0 + lk4);
            a.x = fmaxf(a.x + bb.x, 0.f);
            a.y = fmaxf(a.y + bb.y, 0.f);
            a.z = fmaxf(a.z + bb.z, 0.f);
            a.w = fmaxf(a.w + bb.w, 0.f);
        }
        As[lk4 + 0][lrow] = a.x;
        As[lk4 + 1][lrow] = a.y;
        As[lk4 + 2][lrow] = a.z;
        As[lk4 + 3][lrow] = a.w;

        *(float4*)&Bs[br][bc]     = *(const float4*)(W + (size_t)(k0 + br) * BN + bc);
        *(float4*)&Bs[br + 8][bc] = *(const float4*)(W + (size_t)(k0 + br + 8) * BN + bc);

        __syncthreads();
#pragma unroll
        for (int kk = 0; kk < BK; ++kk) {
            const float4 av  = *(const float4*)&As[kk][ty * 4];
            const float4 b0  = *(const float4*)&Bs[kk][tx * 8];
            const float4 b1v = *(const float4*)&Bs[kk][tx * 8 + 4];
            const float aa[4] = {av.x, av.y, av.z, av.w};
            const float bb[8] = {b0.x, b0.y, b0.z, b0.w, b1v.x, b1v.y, b1v.z, b1v.w};
#pragma unroll
            for (int i = 0; i < 4; ++i)
#pragma unroll
                for (int j = 0; j < 8; ++j)
                    acc[i][j] = fmaf(aa[i], bb[j], acc[i][j]);
        }
        __syncthreads();
    }

#pragma unroll
    for (int i = 0; i < 4; ++i) {
        const int r = bm + ty * 4 + i;
        if (r < NN) {
            const float dv = dinv[r];
            const float d2 = dv * dv;
            float* om = out_main + (size_t)r * BN + tx * 8;
            float* os = out_self + (size_t)r * BN + tx * 8;
#pragma unroll
            for (int j = 0; j < 8; j += 4) {
                float4 v = make_float4(acc[i][j], acc[i][j + 1], acc[i][j + 2], acc[i][j + 3]);
                *(float4*)(om + j) = v;
                float4 s;
                s.x = v.x * d2 + (OUT_BIAS ? bout[tx * 8 + j + 0] : 0.f);
                s.y = v.y * d2 + (OUT_BIAS ? bout[tx * 8 + j + 1] : 0.f);
                s.z = v.z * d2 + (OUT_BIAS ? bout[tx * 8 + j + 2] : 0.f);
                s.w = v.w * d2 + (OUT_BIAS ? bout[tx * 8 + j + 3] : 0.f);
                *(float4*)(os + j) = s;
            }
        }
    }
}

// ---------------- CSR gather: out[d] = init(out[d]) + sum_e h[src_e]*norm ----------------
// 32 lanes per dst node (8 nodes / block), lane owns 4 channels.
__global__ __launch_bounds__(256) void k_gather(const float* __restrict__ h,
                                                const int* __restrict__ rowptr,
                                                const int* __restrict__ csr_src,
                                                const float* __restrict__ dinv,
                                                float* __restrict__ out) {
    const int tid  = threadIdx.x;
    const int node = blockIdx.x * 8 + (tid >> 5);
    if (node >= NN) return;
    const int lane = tid & 31;
    const int c    = lane * 4;
    const int beg  = rowptr[node];
    const int end  = rowptr[node + 1];
    const float dd = dinv[node];

    float4 acc = *(const float4*)(out + (size_t)node * C_HID + c);  // self-loop init from GEMM epilogue

    for (int j0 = beg; j0 < end; j0 += 32) {
        const int n = end - j0;
        int   myS  = 0;
        float myDv = 0.f;
        if (lane < n) {
            myS  = csr_src[j0 + lane];
            myDv = dinv[myS];
        }
        const int m = n < 32 ? n : 32;
        for (int jj = 0; jj < m; ++jj) {
            const int   s    = __shfl(myS, jj, 32);
            const float norm = __shfl(myDv, jj, 32) * dd;
            const float4 v = *(const float4*)(h + (size_t)s * C_HID + c);
            acc.x = fmaf(v.x, norm, acc.x);
            acc.y = fmaf(v.y, norm, acc.y);
            acc.z = fmaf(v.z, norm, acc.z);
            acc.w = fmaf(v.w, norm, acc.w);
        }
    }
    *(float4*)(out + (size_t)node * C_HID + c) = acc;
}

extern "C" void kernel_launch(void* const* d_in, const int* in_sizes, int n_in,
                              void* d_out, int out_size, void* d_ws, size_t ws_size,
                              hipStream_t stream) {
    const float* x  = (const float*)d_in[0];
    const int*   ei = (const int*)d_in[1];
    const float* W1 = (const float*)d_in[2];
    const float* b1 = (const float*)d_in[3];
    const float* W2 = (const float*)d_in[4];
    const float* b2 = (const float*)d_in[5];
    float* out = (float*)d_out;

    const int* src = ei;
    const int* dst = ei + NE;

    // workspace layout (4-byte units)
    int*   cnt     = (int*)d_ws;                      // 50048
    int*   rowptr  = cnt + 50048;                     // 50064 (NN+1)
    int*   cursor  = rowptr + 50064;                  // 50048
    float* dinv    = (float*)(cursor + 50048);        // 50048
    int*   csr_src = (int*)(dinv + 50048);            // 800256
    float* A       = (float*)(csr_src + 800256);      // NN*128  (h buffer)
    float* B       = A + (size_t)NN * C_HID;          // NN*128  (agg buffer)

    hipMemsetAsync(cnt, 0, NN * sizeof(int), stream);
    k_deg<<<(NE + 255) / 256, 256, 0, stream>>>(dst, cnt);
    k_dinv<<<(NN + 255) / 256, 256, 0, stream>>>(cnt, dinv);
    k_scan<<<1, 1024, 0, stream>>>(cnt, rowptr, cursor);
    k_fill<<<(NE + 255) / 256, 256, 0, stream>>>(src, dst, cursor, csr_src);

    const int gblocks  = (NN + 63) / 64;
    const int agblocks = (NN + 7) / 8;
    // layer 1: h1 = x@W1 -> A ;  B = h1*dinv^2 (self-loop init)
    k_gemm<false, false><<<gblocks, 256, 0, stream>>>(x, W1, nullptr, nullptr, dinv, A, B, C_IN);
    // B += gather(h1)
    k_gather<<<agblocks, 256, 0, stream>>>(A, rowptr, csr_src, dinv, B);
    // layer 2: h2 = relu(B + b1)@W2 -> A ; out = h2*dinv^2 + b2 (self-loop init)
    k_gemm<true, true><<<gblocks, 256, 0, stream>>>(B, W2, b1, b2, dinv, A, out, C_HID);
    // out += gather(h2)
    k_gather<<<agblocks, 256, 0, stream>>>(A, rowptr, csr_src, dinv, out);
}

// Round 3
// 462.968 us; speedup vs baseline: 6.3686x; 1.1954x over previous
//
#include <hip/hip_runtime.h>

#define NN 50000
#define NE 800000
#define C_IN 384
#define C_HID 128
#define NB 196  // ceil(NN/256)

// ---------------- degree count (int) ----------------
__global__ __launch_bounds__(256) void k_deg(const int* __restrict__ dst,
                                             int* __restrict__ cnt) {
    int i = blockIdx.x * 256 + threadIdx.x;
    if (i < NE) atomicAdd(&cnt[dst[i]], 1);
}

__global__ __launch_bounds__(256) void k_dinv(const int* __restrict__ cnt,
                                              float* __restrict__ dinv) {
    int i = blockIdx.x * 256 + threadIdx.x;
    if (i < NN) dinv[i] = rsqrtf((float)cnt[i] + 1.0f);  // +1 = self loop
}

// ---------------- hierarchical exclusive scan over NN counts ----------------
__global__ __launch_bounds__(256) void k_bsum(const int* __restrict__ cnt,
                                              int* __restrict__ bsum) {
    __shared__ int part[256];
    const int tid = threadIdx.x;
    const int i = blockIdx.x * 256 + tid;
    part[tid] = (i < NN) ? cnt[i] : 0;
    __syncthreads();
#pragma unroll
    for (int off = 128; off > 0; off >>= 1) {
        if (tid < off) part[tid] += part[tid + off];
        __syncthreads();
    }
    if (tid == 0) bsum[blockIdx.x] = part[0];
}

__global__ __launch_bounds__(256) void k_sbs(const int* __restrict__ bsum,
                                             int* __restrict__ bpre) {
    __shared__ int part[256];
    const int t = threadIdx.x;
    part[t] = (t < NB) ? bsum[t] : 0;
    __syncthreads();
#pragma unroll
    for (int off = 1; off < 256; off <<= 1) {
        int v = (t >= off) ? part[t - off] : 0;
        __syncthreads();
        part[t] += v;
        __syncthreads();
    }
    if (t < NB) bpre[t] = (t == 0) ? 0 : part[t - 1];  // exclusive
}

__global__ __launch_bounds__(256) void k_write(const int* __restrict__ cnt,
                                               const int* __restrict__ bpre,
                                               int* __restrict__ rowptr,
                                               int* __restrict__ cursor) {
    __shared__ int part[256];
    const int t = threadIdx.x;
    const int i = blockIdx.x * 256 + t;
    const int v = (i < NN) ? cnt[i] : 0;
    part[t] = v;
    __syncthreads();
#pragma unroll
    for (int off = 1; off < 256; off <<= 1) {
        int u = (t >= off) ? part[t - off] : 0;
        __syncthreads();
        part[t] += u;
        __syncthreads();
    }
    if (i < NN) {
        const int excl = bpre[blockIdx.x] + part[t] - v;
        rowptr[i] = excl;
        cursor[i] = excl;
        if (i == NN - 1) rowptr[NN] = excl + v;
    }
}

// ---------------- CSR fill ----------------
__global__ __launch_bounds__(256) void k_fill(const int* __restrict__ src,
                                              const int* __restrict__ dst,
                                              int* __restrict__ cursor,
                                              int* __restrict__ csr_src) {
    int e = blockIdx.x * 256 + threadIdx.x;
    if (e < NE) {
        int p = atomicAdd(&cursor[dst[e]], 1);
        csr_src[p] = src[e];
    }
}

// ---------------- fp32 tiled GEMM ----------------
// h = f(X) @ W,  f = (IN_RELU_BIAS ? relu(x + bin[k]) : x)
// out_main[r,c] = h[r,c]
// out_self[r,c] = h[r,c]*dinv[r]^2 + (OUT_BIAS ? bout[c] : 0)   (self-loop init)
template <bool IN_RELU_BIAS, bool OUT_BIAS>
__global__ __launch_bounds__(256) void k_gemm(const float* __restrict__ X,
                                              const float* __restrict__ W,
                                              const float* __restrict__ bin,
                                              const float* __restrict__ bout,
                                              const float* __restrict__ dinv,
                                              float* __restrict__ out_main,
                                              float* __restrict__ out_self,
                                              int K) {
    constexpr int BM = 64, BN = 128, BK = 16;
    __shared__ float As[BK][68];   // transposed [k][m], padded 64->68
    __shared__ float Bs[BK][BN];

    const int tid = threadIdx.x;
    const int bm  = blockIdx.x * BM;
    const int ty  = tid >> 4;     // 0..15 -> rows ty*4 .. ty*4+3
    const int tx  = tid & 15;     // 0..15 -> cols tx*8 .. tx*8+7

    float acc[4][8];
#pragma unroll
    for (int i = 0; i < 4; ++i)
#pragma unroll
        for (int j = 0; j < 8; ++j) acc[i][j] = 0.f;

    const int lrow = tid >> 2;          // 0..63
    const int lk4  = (tid & 3) * 4;     // 0,4,8,12
    int grow = bm + lrow;
    if (grow >= NN) grow = NN - 1;      // clamp (stores are guarded)
    const float* xrow = X + (size_t)grow * K;

    const int br = tid >> 5;            // 0..7
    const int bc = (tid & 31) * 4;      // 0..124

    for (int k0 = 0; k0 < K; k0 += BK) {
        float4 a = *(const float4*)(xrow + k0 + lk4);
        if (IN_RELU_BIAS) {
            float4 bb = *(const float4*)(bin + k0 + lk4);
            a.x = fmaxf(a.x + bb.x, 0.f);
            a.y = fmaxf(a.y + bb.y, 0.f);
            a.z = fmaxf(a.z + bb.z, 0.f);
            a.w = fmaxf(a.w + bb.w, 0.f);
        }
        As[lk4 + 0][lrow] = a.x;
        As[lk4 + 1][lrow] = a.y;
        As[lk4 + 2][lrow] = a.z;
        As[lk4 + 3][lrow] = a.w;

        *(float4*)&Bs[br][bc]     = *(const float4*)(W + (size_t)(k0 + br) * BN + bc);
        *(float4*)&Bs[br + 8][bc] = *(const float4*)(W + (size_t)(k0 + br + 8) * BN + bc);

        __syncthreads();
#pragma unroll
        for (int kk = 0; kk < BK; ++kk) {
            const float4 av  = *(const float4*)&As[kk][ty * 4];
            const float4 b0  = *(const float4*)&Bs[kk][tx * 8];
            const float4 b1v = *(const float4*)&Bs[kk][tx * 8 + 4];
            const float aa[4] = {av.x, av.y, av.z, av.w};
            const float bb[8] = {b0.x, b0.y, b0.z, b0.w, b1v.x, b1v.y, b1v.z, b1v.w};
#pragma unroll
            for (int i = 0; i < 4; ++i)
#pragma unroll
                for (int j = 0; j < 8; ++j)
                    acc[i][j] = fmaf(aa[i], bb[j], acc[i][j]);
        }
        __syncthreads();
    }

#pragma unroll
    for (int i = 0; i < 4; ++i) {
        const int r = bm + ty * 4 + i;
        if (r < NN) {
            const float dv = dinv[r];
            const float d2 = dv * dv;
            float* om = out_main + (size_t)r * BN + tx * 8;
            float* os = out_self + (size_t)r * BN + tx * 8;
#pragma unroll
            for (int j = 0; j < 8; j += 4) {
                float4 v = make_float4(acc[i][j], acc[i][j + 1], acc[i][j + 2], acc[i][j + 3]);
                *(float4*)(om + j) = v;
                float4 s;
                s.x = v.x * d2 + (OUT_BIAS ? bout[tx * 8 + j + 0] : 0.f);
                s.y = v.y * d2 + (OUT_BIAS ? bout[tx * 8 + j + 1] : 0.f);
                s.z = v.z * d2 + (OUT_BIAS ? bout[tx * 8 + j + 2] : 0.f);
                s.w = v.w * d2 + (OUT_BIAS ? bout[tx * 8 + j + 3] : 0.f);
                *(float4*)(os + j) = s;
            }
        }
    }
}

// ---------------- CSR gather: out[d] = init(out[d]) + sum_e h[src_e]*norm ----------------
// 32 lanes per dst node (8 nodes / block), lane owns 4 channels.
__global__ __launch_bounds__(256) void k_gather(const float* __restrict__ h,
                                                const int* __restrict__ rowptr,
                                                const int* __restrict__ csr_src,
                                                const float* __restrict__ dinv,
                                                float* __restrict__ out) {
    const int tid  = threadIdx.x;
    const int node = blockIdx.x * 8 + (tid >> 5);
    if (node >= NN) return;
    const int lane = tid & 31;
    const int c    = lane * 4;
    const int beg  = rowptr[node];
    const int end  = rowptr[node + 1];
    const float dd = dinv[node];

    float4 acc = *(const float4*)(out + (size_t)node * C_HID + c);  // self-loop init from GEMM epilogue

    for (int j0 = beg; j0 < end; j0 += 32) {
        const int n = end - j0;
        int   myS  = 0;
        float myDv = 0.f;
        if (lane < n) {
            myS  = csr_src[j0 + lane];
            myDv = dinv[myS];
        }
        const int m = n < 32 ? n : 32;
        for (int jj = 0; jj < m; ++jj) {
            const int   s    = __shfl(myS, jj, 32);
            const float norm = __shfl(myDv, jj, 32) * dd;
            const float4 v = *(const float4*)(h + (size_t)s * C_HID + c);
            acc.x = fmaf(v.x, norm, acc.x);
            acc.y = fmaf(v.y, norm, acc.y);
            acc.z = fmaf(v.z, norm, acc.z);
            acc.w = fmaf(v.w, norm, acc.w);
        }
    }
    *(float4*)(out + (size_t)node * C_HID + c) = acc;
}

extern "C" void kernel_launch(void* const* d_in, const int* in_sizes, int n_in,
                              void* d_out, int out_size, void* d_ws, size_t ws_size,
                              hipStream_t stream) {
    const float* x  = (const float*)d_in[0];
    const int*   ei = (const int*)d_in[1];
    const float* W1 = (const float*)d_in[2];
    const float* b1 = (const float*)d_in[3];
    const float* W2 = (const float*)d_in[4];
    const float* b2 = (const float*)d_in[5];
    float* out = (float*)d_out;

    const int* src = ei;
    const int* dst = ei + NE;

    // workspace layout (4-byte units)
    int*   cnt     = (int*)d_ws;                      // 50048
    int*   rowptr  = cnt + 50048;                     // 50064 (NN+1)
    int*   cursor  = rowptr + 50064;                  // 50048
    float* dinv    = (float*)(cursor + 50048);        // 50048
    int*   bsum    = (int*)(dinv + 50048);            // 256
    int*   bpre    = bsum + 256;                      // 256
    int*   csr_src = bpre + 256;                      // 800256
    float* A       = (float*)(csr_src + 800256);      // NN*128  (h buffer)
    float* B       = A + (size_t)NN * C_HID;          // NN*128  (agg buffer)

    hipMemsetAsync(cnt, 0, NN * sizeof(int), stream);
    k_deg<<<(NE + 255) / 256, 256, 0, stream>>>(dst, cnt);
    k_dinv<<<NB, 256, 0, stream>>>(cnt, dinv);
    k_bsum<<<NB, 256, 0, stream>>>(cnt, bsum);
    k_sbs<<<1, 256, 0, stream>>>(bsum, bpre);
    k_write<<<NB, 256, 0, stream>>>(cnt, bpre, rowptr, cursor);
    k_fill<<<(NE + 255) / 256, 256, 0, stream>>>(src, dst, cursor, csr_src);

    const int gblocks  = (NN + 63) / 64;
    const int agblocks = (NN + 7) / 8;
    // layer 1: h1 = x@W1 -> A ;  B = h1*dinv^2 (self-loop init)
    k_gemm<false, false><<<gblocks, 256, 0, stream>>>(x, W1, nullptr, nullptr, dinv, A, B, C_IN);
    // B += gather(h1)
    k_gather<<<agblocks, 256, 0, stream>>>(A, rowptr, csr_src, dinv, B);
    // layer 2: h2 = relu(B + b1)@W2 -> A ; out = h2*dinv^2 + b2 (self-loop init)
    k_gemm<true, true><<<gblocks, 256, 0, stream>>>(B, W2, b1, b2, dinv, A, out, C_HID);
    // out += gather(h2)
    k_gather<<<agblocks, 256, 0, stream>>>(A, rowptr, csr_src, dinv, out);
}

// Round 4
// 429.642 us; speedup vs baseline: 6.8625x; 1.0776x over previous
//
#include <hip/hip_runtime.h>

#define NN 50000
#define NE 800000
#define C_IN 384
#define C_HID 128
#define NB 196  // ceil(NN/256)

typedef __attribute__((ext_vector_type(8))) short short8;
typedef __attribute__((ext_vector_type(4))) float f32x4;

__device__ __forceinline__ ushort f2bf(float x) {
    uint u = __float_as_uint(x);
    uint r = (u + 0x7fffu + ((u >> 16) & 1u)) >> 16;  // RNE
    return (ushort)r;
}
__device__ __forceinline__ float bf2f(ushort b) { return __uint_as_float(((uint)b) << 16); }

// ---------------- degree count (int) ----------------
__global__ __launch_bounds__(256) void k_deg(const int* __restrict__ dst,
                                             int* __restrict__ cnt) {
    int i = blockIdx.x * 256 + threadIdx.x;
    if (i < NE) atomicAdd(&cnt[dst[i]], 1);
}

__global__ __launch_bounds__(256) void k_dinv(const int* __restrict__ cnt,
                                              float* __restrict__ dinv) {
    int i = blockIdx.x * 256 + threadIdx.x;
    if (i < NN) dinv[i] = rsqrtf((float)cnt[i] + 1.0f);  // +1 = self loop
}

// ---------------- hierarchical exclusive scan over NN counts ----------------
__global__ __launch_bounds__(256) void k_bsum(const int* __restrict__ cnt,
                                              int* __restrict__ bsum) {
    __shared__ int part[256];
    const int tid = threadIdx.x;
    const int i = blockIdx.x * 256 + tid;
    part[tid] = (i < NN) ? cnt[i] : 0;
    __syncthreads();
#pragma unroll
    for (int off = 128; off > 0; off >>= 1) {
        if (tid < off) part[tid] += part[tid + off];
        __syncthreads();
    }
    if (tid == 0) bsum[blockIdx.x] = part[0];
}

__global__ __launch_bounds__(256) void k_sbs(const int* __restrict__ bsum,
                                             int* __restrict__ bpre) {
    __shared__ int part[256];
    const int t = threadIdx.x;
    part[t] = (t < NB) ? bsum[t] : 0;
    __syncthreads();
#pragma unroll
    for (int off = 1; off < 256; off <<= 1) {
        int v = (t >= off) ? part[t - off] : 0;
        __syncthreads();
        part[t] += v;
        __syncthreads();
    }
    if (t < NB) bpre[t] = (t == 0) ? 0 : part[t - 1];  // exclusive
}

__global__ __launch_bounds__(256) void k_write(const int* __restrict__ cnt,
                                               const int* __restrict__ bpre,
                                               int* __restrict__ rowptr,
                                               int* __restrict__ cursor) {
    __shared__ int part[256];
    const int t = threadIdx.x;
    const int i = blockIdx.x * 256 + t;
    const int v = (i < NN) ? cnt[i] : 0;
    part[t] = v;
    __syncthreads();
#pragma unroll
    for (int off = 1; off < 256; off <<= 1) {
        int u = (t >= off) ? part[t - off] : 0;
        __syncthreads();
        part[t] += u;
        __syncthreads();
    }
    if (i < NN) {
        const int excl = bpre[blockIdx.x] + part[t] - v;
        rowptr[i] = excl;
        cursor[i] = excl;
        if (i == NN - 1) rowptr[NN] = excl + v;
    }
}

// ---------------- CSR fill ----------------
__global__ __launch_bounds__(256) void k_fill(const int* __restrict__ src,
                                              const int* __restrict__ dst,
                                              int* __restrict__ cursor,
                                              int* __restrict__ csr_src) {
    int e = blockIdx.x * 256 + threadIdx.x;
    if (e < NE) {
        int p = atomicAdd(&cursor[dst[e]], 1);
        csr_src[p] = src[e];
    }
}

// ---------------- W -> transposed hi/lo bf16 split (once per launch) ----------------
// W is [K][128] fp32; Wh/Wl are [128][K] bf16 bits (B^T layout for MFMA B-frag)
__global__ __launch_bounds__(256) void k_wconv(const float* __restrict__ W,
                                               ushort* __restrict__ Wh,
                                               ushort* __restrict__ Wl,
                                               int K) {
    int i = blockIdx.x * 256 + threadIdx.x;
    if (i < K * C_HID) {
        int k = i >> 7, n = i & 127;  // N = 128
        float w = W[i];
        ushort h = f2bf(w);
        Wh[n * K + k] = h;
        Wl[n * K + k] = f2bf(w - bf2f(h));
    }
}

// ---------------- split-bf16 MFMA GEMM ----------------
// h = f(X) @ W,  f = (IN_RELU_BIAS ? relu(x + bin[k]) : x)
// out_main[m,n] = h ;  out_self[m,n] = h*dinv[m]^2 + (OUT_BIAS ? bout[n] : 0)
// X fp32 [M][K]; Bh/Bl bf16 [128][K] (W^T hi/lo).  3-pass split: AhBh+AhBl+AlBh.
template <bool IN_RELU_BIAS, bool OUT_BIAS>
__global__ __launch_bounds__(256) void k_gemm_mfma(const float* __restrict__ X,
                                                   const ushort* __restrict__ Bh,
                                                   const ushort* __restrict__ Bl,
                                                   const float* __restrict__ bin,
                                                   const float* __restrict__ bout,
                                                   const float* __restrict__ dinv,
                                                   float* __restrict__ out_main,
                                                   float* __restrict__ out_self,
                                                   int K) {
    constexpr int BM = 64, BK = 32, LDAB = 40;  // stride 40 shorts: 16B-aligned rows, <=2-way banks
    __shared__ ushort Ah[BM][LDAB], Al[BM][LDAB];
    __shared__ ushort Bsh[128][LDAB], Bsl[128][LDAB];

    const int tid = threadIdx.x;
    const int bm = blockIdx.x * BM;

    // A staging: thread owns 8 consecutive k of one row
    const int arow = tid >> 2;         // 0..63
    const int akoff = (tid & 3) * 8;   // 0,8,16,24
    int grow = bm + arow;
    if (grow >= NN) grow = NN - 1;     // clamp (stores guarded)
    const float* xrow = X + (size_t)grow * K;

    // B staging: thread owns 16 consecutive k of one n-row
    const int brow = tid >> 1;         // 0..127
    const int bkoff = (tid & 1) * 16;  // 0,16

    // fragment coords
    const int wv = tid >> 6;           // wave 0..3 -> m-rows [wv*16, wv*16+16)
    const int lane = tid & 63;
    const int fr = lane & 15;
    const int kq = lane >> 4;          // 0..3

    f32x4 acc[8];
#pragma unroll
    for (int t = 0; t < 8; ++t) acc[t] = (f32x4){0.f, 0.f, 0.f, 0.f};

    for (int k0 = 0; k0 < K; k0 += BK) {
        // ---- stage A (fp32 -> hi/lo bf16) ----
        float4 x0 = *(const float4*)(xrow + k0 + akoff);
        float4 x1 = *(const float4*)(xrow + k0 + akoff + 4);
        float xv[8] = {x0.x, x0.y, x0.z, x0.w, x1.x, x1.y, x1.z, x1.w};
        if (IN_RELU_BIAS) {
            float4 b0v = *(const float4*)(bin + k0 + akoff);
            float4 b1v = *(const float4*)(bin + k0 + akoff + 4);
            const float bb[8] = {b0v.x, b0v.y, b0v.z, b0v.w, b1v.x, b1v.y, b1v.z, b1v.w};
#pragma unroll
            for (int j = 0; j < 8; ++j) xv[j] = fmaxf(xv[j] + bb[j], 0.f);
        }
        union { ushort u[8]; short8 v; } ah, al;
#pragma unroll
        for (int j = 0; j < 8; ++j) {
            ushort h = f2bf(xv[j]);
            ah.u[j] = h;
            al.u[j] = f2bf(xv[j] - bf2f(h));
        }
        *(short8*)&Ah[arow][akoff] = ah.v;
        *(short8*)&Al[arow][akoff] = al.v;

        // ---- stage B (pre-split bf16, direct copy) ----
        const ushort* ph = Bh + (size_t)brow * K + k0 + bkoff;
        const ushort* pl = Bl + (size_t)brow * K + k0 + bkoff;
        *(short8*)&Bsh[brow][bkoff] = *(const short8*)(ph);
        *(short8*)&Bsh[brow][bkoff + 8] = *(const short8*)(ph + 8);
        *(short8*)&Bsl[brow][bkoff] = *(const short8*)(pl);
        *(short8*)&Bsl[brow][bkoff + 8] = *(const short8*)(pl + 8);

        __syncthreads();

        const short8 a_h = *(const short8*)&Ah[wv * 16 + fr][kq * 8];
        const short8 a_l = *(const short8*)&Al[wv * 16 + fr][kq * 8];
#pragma unroll
        for (int t = 0; t < 8; ++t) {
            const short8 b_h = *(const short8*)&Bsh[t * 16 + fr][kq * 8];
            const short8 b_l = *(const short8*)&Bsl[t * 16 + fr][kq * 8];
            acc[t] = __builtin_amdgcn_mfma_f32_16x16x32_bf16(a_h, b_h, acc[t], 0, 0, 0);
            acc[t] = __builtin_amdgcn_mfma_f32_16x16x32_bf16(a_h, b_l, acc[t], 0, 0, 0);
            acc[t] = __builtin_amdgcn_mfma_f32_16x16x32_bf16(a_l, b_h, acc[t], 0, 0, 0);
        }
        __syncthreads();
    }

    // ---- epilogue: D(lane,reg): m = bm + wv*16 + kq*4 + reg, n = t*16 + fr ----
#pragma unroll
    for (int r = 0; r < 4; ++r) {
        const int m = bm + wv * 16 + kq * 4 + r;
        if (m < NN) {
            const float dv = dinv[m];
            const float d2 = dv * dv;
            float* om = out_main + (size_t)m * C_HID;
            float* os = out_self + (size_t)m * C_HID;
#pragma unroll
            for (int t = 0; t < 8; ++t) {
                const int n = t * 16 + fr;
                const float v = acc[t][r];
                om[n] = v;
                os[n] = v * d2 + (OUT_BIAS ? bout[n] : 0.f);
            }
        }
    }
}

// ---------------- CSR gather: out[d] = init(out[d]) + sum_e h[src_e]*norm ----------------
// 32 lanes per dst node (8 nodes / block), lane owns 4 channels.
__global__ __launch_bounds__(256) void k_gather(const float* __restrict__ h,
                                                const int* __restrict__ rowptr,
                                                const int* __restrict__ csr_src,
                                                const float* __restrict__ dinv,
                                                float* __restrict__ out) {
    const int tid = threadIdx.x;
    const int node = blockIdx.x * 8 + (tid >> 5);
    if (node >= NN) return;
    const int lane = tid & 31;
    const int c = lane * 4;
    const int beg = rowptr[node];
    const int end = rowptr[node + 1];
    const float dd = dinv[node];

    float4 acc = *(const float4*)(out + (size_t)node * C_HID + c);  // self-loop init from GEMM epilogue

    for (int j0 = beg; j0 < end; j0 += 32) {
        const int n = end - j0;
        int myS = 0;
        float myDv = 0.f;
        if (lane < n) {
            myS = csr_src[j0 + lane];
            myDv = dinv[myS];
        }
        const int m = n < 32 ? n : 32;
        for (int jj = 0; jj < m; ++jj) {
            const int s = __shfl(myS, jj, 32);
            const float norm = __shfl(myDv, jj, 32) * dd;
            const float4 v = *(const float4*)(h + (size_t)s * C_HID + c);
            acc.x = fmaf(v.x, norm, acc.x);
            acc.y = fmaf(v.y, norm, acc.y);
            acc.z = fmaf(v.z, norm, acc.z);
            acc.w = fmaf(v.w, norm, acc.w);
        }
    }
    *(float4*)(out + (size_t)node * C_HID + c) = acc;
}

extern "C" void kernel_launch(void* const* d_in, const int* in_sizes, int n_in,
                              void* d_out, int out_size, void* d_ws, size_t ws_size,
                              hipStream_t stream) {
    const float* x = (const float*)d_in[0];
    const int* ei = (const int*)d_in[1];
    const float* W1 = (const float*)d_in[2];
    const float* b1 = (const float*)d_in[3];
    const float* W2 = (const float*)d_in[4];
    const float* b2 = (const float*)d_in[5];
    float* out = (float*)d_out;

    const int* src = ei;
    const int* dst = ei + NE;

    // workspace layout (4-byte units)
    int* cnt = (int*)d_ws;                       // 50048
    int* rowptr = cnt + 50048;                   // 50064 (NN+1)
    int* cursor = rowptr + 50064;                // 50048
    float* dinv = (float*)(cursor + 50048);      // 50048
    int* bsum = (int*)(dinv + 50048);            // 256
    int* bpre = bsum + 256;                      // 256
    ushort* Wt1h = (ushort*)(bpre + 256);        // 128*384 shorts = 24576 ints
    ushort* Wt1l = Wt1h + 128 * C_IN;            // 24576 ints
    ushort* Wt2h = Wt1l + 128 * C_IN;            // 128*128 shorts = 8192 ints
    ushort* Wt2l = Wt2h + 128 * C_HID;           // 8192 ints
    int* csr_src = (int*)(Wt2l + 128 * C_HID);   // 800256
    float* A = (float*)(csr_src + 800256);       // NN*128  (h buffer)
    float* B = A + (size_t)NN * C_HID;           // NN*128  (agg buffer)

    hipMemsetAsync(cnt, 0, NN * sizeof(int), stream);
    k_wconv<<<(C_IN * C_HID + 255) / 256, 256, 0, stream>>>(W1, Wt1h, Wt1l, C_IN);
    k_wconv<<<(C_HID * C_HID + 255) / 256, 256, 0, stream>>>(W2, Wt2h, Wt2l, C_HID);
    k_deg<<<(NE + 255) / 256, 256, 0, stream>>>(dst, cnt);
    k_dinv<<<NB, 256, 0, stream>>>(cnt, dinv);
    k_bsum<<<NB, 256, 0, stream>>>(cnt, bsum);
    k_sbs<<<1, 256, 0, stream>>>(bsum, bpre);
    k_write<<<NB, 256, 0, stream>>>(cnt, bpre, rowptr, cursor);
    k_fill<<<(NE + 255) / 256, 256, 0, stream>>>(src, dst, cursor, csr_src);

    const int gblocks = (NN + 63) / 64;
    const int agblocks = (NN + 7) / 8;
    // layer 1: h1 = x@W1 -> A ;  B = h1*dinv^2 (self-loop init)
    k_gemm_mfma<false, false><<<gblocks, 256, 0, stream>>>(x, Wt1h, Wt1l, nullptr, nullptr, dinv, A, B, C_IN);
    // B += gather(h1)
    k_gather<<<agblocks, 256, 0, stream>>>(A, rowptr, csr_src, dinv, B);
    // layer 2: h2 = relu(B + b1)@W2 -> A ; out = h2*dinv^2 + b2 (self-loop init)
    k_gemm_mfma<true, true><<<gblocks, 256, 0, stream>>>(B, Wt2h, Wt2l, b1, b2, dinv, A, out, C_HID);
    // out += gather(h2)
    k_gather<<<agblocks, 256, 0, stream>>>(A, rowptr, csr_src, dinv, out);
}

// Round 5
// 356.385 us; speedup vs baseline: 8.2732x; 1.2056x over previous
//
#include <hip/hip_runtime.h>

#define NN 50000
#define NE 800000
#define C_IN 384
#define C_HID 128
#define NB 196  // ceil(NN/256)

typedef __attribute__((ext_vector_type(8))) short short8;
typedef __attribute__((ext_vector_type(4))) float f32x4;
typedef __attribute__((ext_vector_type(4))) unsigned short us4;

__device__ __forceinline__ ushort f2bf(float x) {
    uint u = __float_as_uint(x);
    uint r = (u + 0x7fffu + ((u >> 16) & 1u)) >> 16;  // RNE
    return (ushort)r;
}
__device__ __forceinline__ float bf2f(ushort b) { return __uint_as_float(((uint)b) << 16); }

// ---------------- degree count (int) ----------------
__global__ __launch_bounds__(256) void k_deg(const int* __restrict__ dst,
                                             int* __restrict__ cnt) {
    int i = blockIdx.x * 256 + threadIdx.x;
    if (i < NE) atomicAdd(&cnt[dst[i]], 1);
}

__global__ __launch_bounds__(256) void k_dinv(const int* __restrict__ cnt,
                                              float* __restrict__ dinv) {
    int i = blockIdx.x * 256 + threadIdx.x;
    if (i < NN) dinv[i] = rsqrtf((float)cnt[i] + 1.0f);  // +1 = self loop
}

// ---------------- hierarchical exclusive scan over NN counts ----------------
__global__ __launch_bounds__(256) void k_bsum(const int* __restrict__ cnt,
                                              int* __restrict__ bsum) {
    __shared__ int part[256];
    const int tid = threadIdx.x;
    const int i = blockIdx.x * 256 + tid;
    part[tid] = (i < NN) ? cnt[i] : 0;
    __syncthreads();
#pragma unroll
    for (int off = 128; off > 0; off >>= 1) {
        if (tid < off) part[tid] += part[tid + off];
        __syncthreads();
    }
    if (tid == 0) bsum[blockIdx.x] = part[0];
}

__global__ __launch_bounds__(256) void k_sbs(const int* __restrict__ bsum,
                                             int* __restrict__ bpre) {
    __shared__ int part[256];
    const int t = threadIdx.x;
    part[t] = (t < NB) ? bsum[t] : 0;
    __syncthreads();
#pragma unroll
    for (int off = 1; off < 256; off <<= 1) {
        int v = (t >= off) ? part[t - off] : 0;
        __syncthreads();
        part[t] += v;
        __syncthreads();
    }
    if (t < NB) bpre[t] = (t == 0) ? 0 : part[t - 1];  // exclusive
}

__global__ __launch_bounds__(256) void k_write(const int* __restrict__ cnt,
                                               const int* __restrict__ bpre,
                                               int* __restrict__ rowptr,
                                               int* __restrict__ cursor) {
    __shared__ int part[256];
    const int t = threadIdx.x;
    const int i = blockIdx.x * 256 + t;
    const int v = (i < NN) ? cnt[i] : 0;
    part[t] = v;
    __syncthreads();
#pragma unroll
    for (int off = 1; off < 256; off <<= 1) {
        int u = (t >= off) ? part[t - off] : 0;
        __syncthreads();
        part[t] += u;
        __syncthreads();
    }
    if (i < NN) {
        const int excl = bpre[blockIdx.x] + part[t] - v;
        rowptr[i] = excl;
        cursor[i] = excl;
        if (i == NN - 1) rowptr[NN] = excl + v;
    }
}

// ---------------- CSR fill: entry = (src, dinv[src] bits) ----------------
__global__ __launch_bounds__(256) void k_fill(const int* __restrict__ src,
                                              const int* __restrict__ dst,
                                              const float* __restrict__ dinv,
                                              int* __restrict__ cursor,
                                              int2* __restrict__ csr) {
    int e = blockIdx.x * 256 + threadIdx.x;
    if (e < NE) {
        int s = src[e];
        int p = atomicAdd(&cursor[dst[e]], 1);
        csr[p] = make_int2(s, __float_as_int(dinv[s]));
    }
}

// ---------------- W -> transposed hi/lo bf16 split (once per launch) ----------------
// W is [K][128] fp32; Wh/Wl are [128][K] bf16 bits (B^T layout for MFMA B-frag)
__global__ __launch_bounds__(256) void k_wconv(const float* __restrict__ W,
                                               ushort* __restrict__ Wh,
                                               ushort* __restrict__ Wl,
                                               int K) {
    int i = blockIdx.x * 256 + threadIdx.x;
    if (i < K * C_HID) {
        int k = i >> 7, n = i & 127;  // N = 128
        float w = W[i];
        ushort h = f2bf(w);
        Wh[n * K + k] = h;
        Wl[n * K + k] = f2bf(w - bf2f(h));
    }
}

// ---------------- split-bf16 MFMA GEMM ----------------
// h = f(X) @ W,  f = (IN_RELU_BIAS ? relu(x + bin[k]) : x)
// out_main[m,n] = bf16(h)  (feeds the gather)
// out_self[m,n] = h*dinv[m]^2 + (OUT_BIAS ? bout[n] : 0)   (fp32 self-loop init)
template <bool IN_RELU_BIAS, bool OUT_BIAS>
__global__ __launch_bounds__(256) void k_gemm_mfma(const float* __restrict__ X,
                                                   const ushort* __restrict__ Bh,
                                                   const ushort* __restrict__ Bl,
                                                   const float* __restrict__ bin,
                                                   const float* __restrict__ bout,
                                                   const float* __restrict__ dinv,
                                                   ushort* __restrict__ out_main,
                                                   float* __restrict__ out_self,
                                                   int K) {
    constexpr int BM = 64, BK = 32, LDAB = 40;  // stride 40 shorts: 16B-aligned rows, <=2-way banks
    __shared__ ushort Ah[BM][LDAB], Al[BM][LDAB];
    __shared__ ushort Bsh[128][LDAB], Bsl[128][LDAB];

    const int tid = threadIdx.x;
    const int bm = blockIdx.x * BM;

    // A staging: thread owns 8 consecutive k of one row
    const int arow = tid >> 2;         // 0..63
    const int akoff = (tid & 3) * 8;   // 0,8,16,24
    int grow = bm + arow;
    if (grow >= NN) grow = NN - 1;     // clamp (stores guarded)
    const float* xrow = X + (size_t)grow * K;

    // B staging: thread owns 16 consecutive k of one n-row
    const int brow = tid >> 1;         // 0..127
    const int bkoff = (tid & 1) * 16;  // 0,16

    // fragment coords
    const int wv = tid >> 6;           // wave 0..3 -> m-rows [wv*16, wv*16+16)
    const int lane = tid & 63;
    const int fr = lane & 15;
    const int kq = lane >> 4;          // 0..3

    f32x4 acc[8];
#pragma unroll
    for (int t = 0; t < 8; ++t) acc[t] = (f32x4){0.f, 0.f, 0.f, 0.f};

    for (int k0 = 0; k0 < K; k0 += BK) {
        // ---- stage A (fp32 -> hi/lo bf16) ----
        float4 x0 = *(const float4*)(xrow + k0 + akoff);
        float4 x1 = *(const float4*)(xrow + k0 + akoff + 4);
        float xv[8] = {x0.x, x0.y, x0.z, x0.w, x1.x, x1.y, x1.z, x1.w};
        if (IN_RELU_BIAS) {
            float4 b0v = *(const float4*)(bin + k0 + akoff);
            float4 b1v = *(const float4*)(bin + k0 + akoff + 4);
            const float bb[8] = {b0v.x, b0v.y, b0v.z, b0v.w, b1v.x, b1v.y, b1v.z, b1v.w};
#pragma unroll
            for (int j = 0; j < 8; ++j) xv[j] = fmaxf(xv[j] + bb[j], 0.f);
        }
        union { ushort u[8]; short8 v; } ah, al;
#pragma unroll
        for (int j = 0; j < 8; ++j) {
            ushort h = f2bf(xv[j]);
            ah.u[j] = h;
            al.u[j] = f2bf(xv[j] - bf2f(h));
        }
        *(short8*)&Ah[arow][akoff] = ah.v;
        *(short8*)&Al[arow][akoff] = al.v;

        // ---- stage B (pre-split bf16, direct copy) ----
        const ushort* ph = Bh + (size_t)brow * K + k0 + bkoff;
        const ushort* pl = Bl + (size_t)brow * K + k0 + bkoff;
        *(short8*)&Bsh[brow][bkoff] = *(const short8*)(ph);
        *(short8*)&Bsh[brow][bkoff + 8] = *(const short8*)(ph + 8);
        *(short8*)&Bsl[brow][bkoff] = *(const short8*)(pl);
        *(short8*)&Bsl[brow][bkoff + 8] = *(const short8*)(pl + 8);

        __syncthreads();

        const short8 a_h = *(const short8*)&Ah[wv * 16 + fr][kq * 8];
        const short8 a_l = *(const short8*)&Al[wv * 16 + fr][kq * 8];
#pragma unroll
        for (int t = 0; t < 8; ++t) {
            const short8 b_h = *(const short8*)&Bsh[t * 16 + fr][kq * 8];
            const short8 b_l = *(const short8*)&Bsl[t * 16 + fr][kq * 8];
            acc[t] = __builtin_amdgcn_mfma_f32_16x16x32_bf16(a_h, b_h, acc[t], 0, 0, 0);
            acc[t] = __builtin_amdgcn_mfma_f32_16x16x32_bf16(a_h, b_l, acc[t], 0, 0, 0);
            acc[t] = __builtin_amdgcn_mfma_f32_16x16x32_bf16(a_l, b_h, acc[t], 0, 0, 0);
        }
        __syncthreads();
    }

    // ---- epilogue: D(lane,reg): m = bm + wv*16 + kq*4 + reg, n = t*16 + fr ----
#pragma unroll
    for (int r = 0; r < 4; ++r) {
        const int m = bm + wv * 16 + kq * 4 + r;
        if (m < NN) {
            const float dv = dinv[m];
            const float d2 = dv * dv;
            ushort* om = out_main + (size_t)m * C_HID;
            float* os = out_self + (size_t)m * C_HID;
#pragma unroll
            for (int t = 0; t < 8; ++t) {
                const int n = t * 16 + fr;
                const float v = acc[t][r];
                om[n] = f2bf(v);
                os[n] = v * d2 + (OUT_BIAS ? bout[n] : 0.f);
            }
        }
    }
}

// ---------------- CSR gather: out[d] = init(out[d]) + sum_e bf16(h[src_e])*norm ----------------
// 32 lanes per dst node (8 nodes / block), lane owns 4 channels.  4-deep load MLP.
__global__ __launch_bounds__(256) void k_gather(const ushort* __restrict__ h,
                                                const int* __restrict__ rowptr,
                                                const int2* __restrict__ csr,
                                                const float* __restrict__ dinv,
                                                float* __restrict__ out) {
    const int tid = threadIdx.x;
    const int node = blockIdx.x * 8 + (tid >> 5);
    if (node >= NN) return;
    const int lane = tid & 31;
    const int c = lane * 4;
    const int beg = rowptr[node];
    const int end = rowptr[node + 1];
    const float dd = dinv[node];

    float4 acc = *(const float4*)(out + (size_t)node * C_HID + c);  // self-loop init from GEMM epilogue

    for (int j0 = beg; j0 < end; j0 += 32) {
        const int n = end - j0;
        int myS = 0;
        float myDv = 0.f;
        if (lane < n) {
            int2 e = csr[j0 + lane];
            myS = e.x;
            myDv = __int_as_float(e.y);
        }
        const int m = n < 32 ? n : 32;
        int jj = 0;
        for (; jj + 4 <= m; jj += 4) {
            const int s0 = __shfl(myS, jj + 0, 32);
            const int s1 = __shfl(myS, jj + 1, 32);
            const int s2 = __shfl(myS, jj + 2, 32);
            const int s3 = __shfl(myS, jj + 3, 32);
            const float n0 = __shfl(myDv, jj + 0, 32) * dd;
            const float n1 = __shfl(myDv, jj + 1, 32) * dd;
            const float n2 = __shfl(myDv, jj + 2, 32) * dd;
            const float n3 = __shfl(myDv, jj + 3, 32) * dd;
            const us4 u0 = *(const us4*)(h + (size_t)s0 * C_HID + c);
            const us4 u1 = *(const us4*)(h + (size_t)s1 * C_HID + c);
            const us4 u2 = *(const us4*)(h + (size_t)s2 * C_HID + c);
            const us4 u3 = *(const us4*)(h + (size_t)s3 * C_HID + c);
            acc.x = fmaf(bf2f(u0[0]), n0, acc.x);
            acc.y = fmaf(bf2f(u0[1]), n0, acc.y);
            acc.z = fmaf(bf2f(u0[2]), n0, acc.z);
            acc.w = fmaf(bf2f(u0[3]), n0, acc.w);
            acc.x = fmaf(bf2f(u1[0]), n1, acc.x);
            acc.y = fmaf(bf2f(u1[1]), n1, acc.y);
            acc.z = fmaf(bf2f(u1[2]), n1, acc.z);
            acc.w = fmaf(bf2f(u1[3]), n1, acc.w);
            acc.x = fmaf(bf2f(u2[0]), n2, acc.x);
            acc.y = fmaf(bf2f(u2[1]), n2, acc.y);
            acc.z = fmaf(bf2f(u2[2]), n2, acc.z);
            acc.w = fmaf(bf2f(u2[3]), n2, acc.w);
            acc.x = fmaf(bf2f(u3[0]), n3, acc.x);
            acc.y = fmaf(bf2f(u3[1]), n3, acc.y);
            acc.z = fmaf(bf2f(u3[2]), n3, acc.z);
            acc.w = fmaf(bf2f(u3[3]), n3, acc.w);
        }
        for (; jj < m; ++jj) {
            const int s = __shfl(myS, jj, 32);
            const float nw = __shfl(myDv, jj, 32) * dd;
            const us4 u = *(const us4*)(h + (size_t)s * C_HID + c);
            acc.x = fmaf(bf2f(u[0]), nw, acc.x);
            acc.y = fmaf(bf2f(u[1]), nw, acc.y);
            acc.z = fmaf(bf2f(u[2]), nw, acc.z);
            acc.w = fmaf(bf2f(u[3]), nw, acc.w);
        }
    }
    *(float4*)(out + (size_t)node * C_HID + c) = acc;
}

extern "C" void kernel_launch(void* const* d_in, const int* in_sizes, int n_in,
                              void* d_out, int out_size, void* d_ws, size_t ws_size,
                              hipStream_t stream) {
    const float* x = (const float*)d_in[0];
    const int* ei = (const int*)d_in[1];
    const float* W1 = (const float*)d_in[2];
    const float* b1 = (const float*)d_in[3];
    const float* W2 = (const float*)d_in[4];
    const float* b2 = (const float*)d_in[5];
    float* out = (float*)d_out;

    const int* src = ei;
    const int* dst = ei + NE;

    // workspace layout (4-byte units)
    int* cnt = (int*)d_ws;                       // 50048
    int* rowptr = cnt + 50048;                   // 50064 (NN+1)
    int* cursor = rowptr + 50064;                // 50048
    float* dinv = (float*)(cursor + 50048);      // 50048
    int* bsum = (int*)(dinv + 50048);            // 256
    int* bpre = bsum + 256;                      // 256
    ushort* Wt1h = (ushort*)(bpre + 256);        // 128*384 shorts = 24576 ints
    ushort* Wt1l = Wt1h + 128 * C_IN;            // 24576 ints
    ushort* Wt2h = Wt1l + 128 * C_IN;            // 128*128 shorts = 8192 ints
    ushort* Wt2l = Wt2h + 128 * C_HID;           // 8192 ints
    int2* csr = (int2*)(Wt2l + 128 * C_HID);     // NE int2 = 1600000 ints
    ushort* A_bf = (ushort*)(csr + NE);          // NN*128 shorts = 3.2M ints (h bf16)
    float* B = (float*)(A_bf + (size_t)NN * C_HID);  // NN*128 fp32 (agg buffer)

    hipMemsetAsync(cnt, 0, NN * sizeof(int), stream);
    k_wconv<<<(C_IN * C_HID + 255) / 256, 256, 0, stream>>>(W1, Wt1h, Wt1l, C_IN);
    k_wconv<<<(C_HID * C_HID + 255) / 256, 256, 0, stream>>>(W2, Wt2h, Wt2l, C_HID);
    k_deg<<<(NE + 255) / 256, 256, 0, stream>>>(dst, cnt);
    k_dinv<<<NB, 256, 0, stream>>>(cnt, dinv);
    k_bsum<<<NB, 256, 0, stream>>>(cnt, bsum);
    k_sbs<<<1, 256, 0, stream>>>(bsum, bpre);
    k_write<<<NB, 256, 0, stream>>>(cnt, bpre, rowptr, cursor);
    k_fill<<<(NE + 255) / 256, 256, 0, stream>>>(src, dst, dinv, cursor, csr);

    const int gblocks = (NN + 63) / 64;
    const int agblocks = (NN + 7) / 8;
    // layer 1: h1 = x@W1 -> A_bf (bf16) ;  B = h1*dinv^2 (fp32 self-loop init)
    k_gemm_mfma<false, false><<<gblocks, 256, 0, stream>>>(x, Wt1h, Wt1l, nullptr, nullptr, dinv, A_bf, B, C_IN);
    // B += gather(h1)
    k_gather<<<agblocks, 256, 0, stream>>>(A_bf, rowptr, csr, dinv, B);
    // layer 2: h2 = relu(B + b1)@W2 -> A_bf ; out = h2*dinv^2 + b2 (self-loop init)
    k_gemm_mfma<true, true><<<gblocks, 256, 0, stream>>>(B, Wt2h, Wt2l, b1, b2, dinv, A_bf, out, C_HID);
    // out += gather(h2)
    k_gather<<<agblocks, 256, 0, stream>>>(A_bf, rowptr, csr, dinv, out);
}

// Round 6
// 345.483 us; speedup vs baseline: 8.5343x; 1.0316x over previous
//
#include <hip/hip_runtime.h>

#define NN 50000
#define NE 800000
#define C_IN 384
#define C_HID 128
#define NB 196  // ceil(NN/256)

typedef __attribute__((ext_vector_type(8))) short short8;
typedef __attribute__((ext_vector_type(4))) float f32x4;
typedef __attribute__((ext_vector_type(4))) unsigned short us4;

__device__ __forceinline__ ushort f2bf(float x) {
    uint u = __float_as_uint(x);
    uint r = (u + 0x7fffu + ((u >> 16) & 1u)) >> 16;  // RNE
    return (ushort)r;
}
__device__ __forceinline__ float bf2f(ushort b) { return __uint_as_float(((uint)b) << 16); }

// ---------------- degree count (int) ----------------
__global__ __launch_bounds__(256) void k_deg(const int* __restrict__ dst,
                                             int* __restrict__ cnt) {
    int i = blockIdx.x * 256 + threadIdx.x;
    if (i < NE) atomicAdd(&cnt[dst[i]], 1);
}

__global__ __launch_bounds__(256) void k_dinv(const int* __restrict__ cnt,
                                              float* __restrict__ dinv) {
    int i = blockIdx.x * 256 + threadIdx.x;
    if (i < NN) dinv[i] = rsqrtf((float)cnt[i] + 1.0f);  // +1 = self loop
}

// ---------------- hierarchical exclusive scan over NN counts ----------------
__global__ __launch_bounds__(256) void k_bsum(const int* __restrict__ cnt,
                                              int* __restrict__ bsum) {
    __shared__ int part[256];
    const int tid = threadIdx.x;
    const int i = blockIdx.x * 256 + tid;
    part[tid] = (i < NN) ? cnt[i] : 0;
    __syncthreads();
#pragma unroll
    for (int off = 128; off > 0; off >>= 1) {
        if (tid < off) part[tid] += part[tid + off];
        __syncthreads();
    }
    if (tid == 0) bsum[blockIdx.x] = part[0];
}

__global__ __launch_bounds__(256) void k_sbs(const int* __restrict__ bsum,
                                             int* __restrict__ bpre) {
    __shared__ int part[256];
    const int t = threadIdx.x;
    part[t] = (t < NB) ? bsum[t] : 0;
    __syncthreads();
#pragma unroll
    for (int off = 1; off < 256; off <<= 1) {
        int v = (t >= off) ? part[t - off] : 0;
        __syncthreads();
        part[t] += v;
        __syncthreads();
    }
    if (t < NB) bpre[t] = (t == 0) ? 0 : part[t - 1];  // exclusive
}

__global__ __launch_bounds__(256) void k_write(const int* __restrict__ cnt,
                                               const int* __restrict__ bpre,
                                               int* __restrict__ rowptr,
                                               int* __restrict__ cursor) {
    __shared__ int part[256];
    const int t = threadIdx.x;
    const int i = blockIdx.x * 256 + t;
    const int v = (i < NN) ? cnt[i] : 0;
    part[t] = v;
    __syncthreads();
#pragma unroll
    for (int off = 1; off < 256; off <<= 1) {
        int u = (t >= off) ? part[t - off] : 0;
        __syncthreads();
        part[t] += u;
        __syncthreads();
    }
    if (i < NN) {
        const int excl = bpre[blockIdx.x] + part[t] - v;
        rowptr[i] = excl;
        cursor[i] = excl;
        if (i == NN - 1) rowptr[NN] = excl + v;
    }
}

// ---------------- CSR fill: entry = (src, dinv[src] bits) ----------------
__global__ __launch_bounds__(256) void k_fill(const int* __restrict__ src,
                                              const int* __restrict__ dst,
                                              const float* __restrict__ dinv,
                                              int* __restrict__ cursor,
                                              int2* __restrict__ csr) {
    int e = blockIdx.x * 256 + threadIdx.x;
    if (e < NE) {
        int s = src[e];
        int p = atomicAdd(&cursor[dst[e]], 1);
        csr[p] = make_int2(s, __float_as_int(dinv[s]));
    }
}

// ---------------- W -> fragment-linear hi/lo bf16 split (once per launch) ----------------
// W is [K][128] fp32.  Wt layout: per 64-k block (32 KB = 16384 shorts):
//   hi region [0,8192): chunk (khalf,t) of 512 shorts, lane-ordered:
//     short index = (khalf*8 + t)*512 + lane*8 + j   where lane = kq*16 + fr
//     holds B[n = t*16+fr][k = blk*64 + khalf*32 + kq*8 + j]
//   lo region at +8192.
// LDS staging becomes a straight 32 KB memcpy; all ds_read_b128 lane-contiguous.
__global__ __launch_bounds__(256) void k_wconv(const float* __restrict__ W,
                                               ushort* __restrict__ Wt,
                                               int K) {
    int i = blockIdx.x * 256 + threadIdx.x;
    if (i < K * C_HID) {
        int k = i >> 7, n = i & 127;  // N = 128
        float w = W[i];
        ushort h = f2bf(w);
        ushort l = f2bf(w - bf2f(h));
        int blk = k >> 6, khalf = (k >> 5) & 1, kq = (k >> 3) & 3, j = k & 7;
        int t = n >> 4, fr = n & 15, lane = kq * 16 + fr;
        size_t off = (size_t)blk * 16384 + (size_t)((khalf * 8 + t) * 64 + lane) * 8 + j;
        Wt[off] = h;
        Wt[off + 8192] = l;
    }
}

// ---------------- split-bf16 MFMA GEMM (A direct-to-reg, conflict-free B LDS) ----------------
// h = f(X) @ W,  f = (IN_RELU_BIAS ? relu(x + bin[k]) : x)
// out_main[m,n] = bf16(h)  (feeds the gather)
// out_self[m,n] = h*dinv[m]^2 + (OUT_BIAS ? bout[n] : 0)   (fp32 self-loop init)
template <bool IN_RELU_BIAS, bool OUT_BIAS>
__global__ __launch_bounds__(256) void k_gemm_mfma(const float* __restrict__ X,
                                                   const ushort* __restrict__ Wt,
                                                   const float* __restrict__ bin,
                                                   const float* __restrict__ bout,
                                                   const float* __restrict__ dinv,
                                                   ushort* __restrict__ out_main,
                                                   float* __restrict__ out_self,
                                                   int K) {
    __shared__ short8 Bs8[2048];  // 32 KB, one 64-k block of W (hi 16K + lo 16K)

    const int tid = threadIdx.x;
    const int bm = blockIdx.x * 64;
    const int wv = tid >> 6;      // wave -> m rows [bm+wv*16, +16)
    const int lane = tid & 63;
    const int fr = lane & 15;
    const int kq = lane >> 4;

    int row = bm + wv * 16 + fr;
    if (row >= NN) row = NN - 1;  // clamp (stores guarded)
    const float* xrow = X + (size_t)row * K + kq * 8;
    const short8* Wt8 = (const short8*)Wt;

    f32x4 acc[8];
#pragma unroll
    for (int t = 0; t < 8; ++t) acc[t] = (f32x4){0.f, 0.f, 0.f, 0.f};

    for (int k0 = 0; k0 < K; k0 += 64) {
        // ---- A: direct global -> regs (lane owns row fr, k = kq*8..+8, both k-halves) ----
        const float* ap = xrow + k0;
        float4 xa0 = *(const float4*)(ap);
        float4 xa1 = *(const float4*)(ap + 4);
        float4 xb0 = *(const float4*)(ap + 32);
        float4 xb1 = *(const float4*)(ap + 36);

        // ---- B: straight 32 KB copy to regs (contiguous, coalesced) ----
        short8 tmp[8];
        const short8* gB = Wt8 + (size_t)(k0 >> 6) * 2048;
#pragma unroll
        for (int i = 0; i < 8; ++i) tmp[i] = gB[i * 256 + tid];

        // ---- convert A to hi/lo bf16 (truncation split; err ~2^-16) ----
        float xv[16] = {xa0.x, xa0.y, xa0.z, xa0.w, xa1.x, xa1.y, xa1.z, xa1.w,
                        xb0.x, xb0.y, xb0.z, xb0.w, xb1.x, xb1.y, xb1.z, xb1.w};
        if (IN_RELU_BIAS) {
            const float* bp = bin + k0 + kq * 8;
            float4 b0 = *(const float4*)(bp);
            float4 b1 = *(const float4*)(bp + 4);
            float4 b2 = *(const float4*)(bp + 32);
            float4 b3 = *(const float4*)(bp + 36);
            const float bb[16] = {b0.x, b0.y, b0.z, b0.w, b1.x, b1.y, b1.z, b1.w,
                                  b2.x, b2.y, b2.z, b2.w, b3.x, b3.y, b3.z, b3.w};
#pragma unroll
            for (int j = 0; j < 16; ++j) xv[j] = fmaxf(xv[j] + bb[j], 0.f);
        }
        union { ushort u[8]; short8 v; } ah0, al0, ah1, al1;
#pragma unroll
        for (int j = 0; j < 8; ++j) {
            uint u = __float_as_uint(xv[j]);
            ah0.u[j] = (ushort)(u >> 16);
            al0.u[j] = (ushort)(__float_as_uint(xv[j] - __uint_as_float(u & 0xffff0000u)) >> 16);
            uint w = __float_as_uint(xv[8 + j]);
            ah1.u[j] = (ushort)(w >> 16);
            al1.u[j] = (ushort)(__float_as_uint(xv[8 + j] - __uint_as_float(w & 0xffff0000u)) >> 16);
        }

        __syncthreads();  // previous iter's Bs readers done
#pragma unroll
        for (int i = 0; i < 8; ++i) Bs8[i * 256 + tid] = tmp[i];
        __syncthreads();  // Bs visible

        // ---- MFMA: 48 per wave per iter, lane-contiguous b128 LDS reads ----
#pragma unroll
        for (int t = 0; t < 8; ++t) {
            const short8 bh0 = Bs8[t * 64 + lane];
            const short8 bl0 = Bs8[1024 + t * 64 + lane];
            const short8 bh1 = Bs8[(8 + t) * 64 + lane];
            const short8 bl1 = Bs8[1024 + (8 + t) * 64 + lane];
            acc[t] = __builtin_amdgcn_mfma_f32_16x16x32_bf16(ah0.v, bh0, acc[t], 0, 0, 0);
            acc[t] = __builtin_amdgcn_mfma_f32_16x16x32_bf16(ah0.v, bl0, acc[t], 0, 0, 0);
            acc[t] = __builtin_amdgcn_mfma_f32_16x16x32_bf16(al0.v, bh0, acc[t], 0, 0, 0);
            acc[t] = __builtin_amdgcn_mfma_f32_16x16x32_bf16(ah1.v, bh1, acc[t], 0, 0, 0);
            acc[t] = __builtin_amdgcn_mfma_f32_16x16x32_bf16(ah1.v, bl1, acc[t], 0, 0, 0);
            acc[t] = __builtin_amdgcn_mfma_f32_16x16x32_bf16(al1.v, bh1, acc[t], 0, 0, 0);
        }
    }

    // ---- epilogue: D(lane,reg): m = bm + wv*16 + kq*4 + r, n = t*16 + fr ----
#pragma unroll
    for (int r = 0; r < 4; ++r) {
        const int m = bm + wv * 16 + kq * 4 + r;
        if (m < NN) {
            const float dv = dinv[m];
            const float d2 = dv * dv;
            ushort* om = out_main + (size_t)m * C_HID;
            float* os = out_self + (size_t)m * C_HID;
#pragma unroll
            for (int t = 0; t < 8; ++t) {
                const int n = t * 16 + fr;
                const float v = acc[t][r];
                om[n] = f2bf(v);
                os[n] = v * d2 + (OUT_BIAS ? bout[n] : 0.f);
            }
        }
    }
}

// ---------------- CSR gather: out[d] = init(out[d]) + sum_e bf16(h[src_e])*norm ----------------
// 32 lanes per dst node (8 nodes / block), lane owns 4 channels.  4-deep load MLP.
__global__ __launch_bounds__(256) void k_gather(const ushort* __restrict__ h,
                                                const int* __restrict__ rowptr,
                                                const int2* __restrict__ csr,
                                                const float* __restrict__ dinv,
                                                float* __restrict__ out) {
    const int tid = threadIdx.x;
    const int node = blockIdx.x * 8 + (tid >> 5);
    if (node >= NN) return;
    const int lane = tid & 31;
    const int c = lane * 4;
    const int beg = rowptr[node];
    const int end = rowptr[node + 1];
    const float dd = dinv[node];

    float4 acc = *(const float4*)(out + (size_t)node * C_HID + c);  // self-loop init from GEMM epilogue

    for (int j0 = beg; j0 < end; j0 += 32) {
        const int n = end - j0;
        int myS = 0;
        float myDv = 0.f;
        if (lane < n) {
            int2 e = csr[j0 + lane];
            myS = e.x;
            myDv = __int_as_float(e.y);
        }
        const int m = n < 32 ? n : 32;
        int jj = 0;
        for (; jj + 4 <= m; jj += 4) {
            const int s0 = __shfl(myS, jj + 0, 32);
            const int s1 = __shfl(myS, jj + 1, 32);
            const int s2 = __shfl(myS, jj + 2, 32);
            const int s3 = __shfl(myS, jj + 3, 32);
            const float n0 = __shfl(myDv, jj + 0, 32) * dd;
            const float n1 = __shfl(myDv, jj + 1, 32) * dd;
            const float n2 = __shfl(myDv, jj + 2, 32) * dd;
            const float n3 = __shfl(myDv, jj + 3, 32) * dd;
            const us4 u0 = *(const us4*)(h + (size_t)s0 * C_HID + c);
            const us4 u1 = *(const us4*)(h + (size_t)s1 * C_HID + c);
            const us4 u2 = *(const us4*)(h + (size_t)s2 * C_HID + c);
            const us4 u3 = *(const us4*)(h + (size_t)s3 * C_HID + c);
            acc.x = fmaf(bf2f(u0[0]), n0, acc.x);
            acc.y = fmaf(bf2f(u0[1]), n0, acc.y);
            acc.z = fmaf(bf2f(u0[2]), n0, acc.z);
            acc.w = fmaf(bf2f(u0[3]), n0, acc.w);
            acc.x = fmaf(bf2f(u1[0]), n1, acc.x);
            acc.y = fmaf(bf2f(u1[1]), n1, acc.y);
            acc.z = fmaf(bf2f(u1[2]), n1, acc.z);
            acc.w = fmaf(bf2f(u1[3]), n1, acc.w);
            acc.x = fmaf(bf2f(u2[0]), n2, acc.x);
            acc.y = fmaf(bf2f(u2[1]), n2, acc.y);
            acc.z = fmaf(bf2f(u2[2]), n2, acc.z);
            acc.w = fmaf(bf2f(u2[3]), n2, acc.w);
            acc.x = fmaf(bf2f(u3[0]), n3, acc.x);
            acc.y = fmaf(bf2f(u3[1]), n3, acc.y);
            acc.z = fmaf(bf2f(u3[2]), n3, acc.z);
            acc.w = fmaf(bf2f(u3[3]), n3, acc.w);
        }
        for (; jj < m; ++jj) {
            const int s = __shfl(myS, jj, 32);
            const float nw = __shfl(myDv, jj, 32) * dd;
            const us4 u = *(const us4*)(h + (size_t)s * C_HID + c);
            acc.x = fmaf(bf2f(u[0]), nw, acc.x);
            acc.y = fmaf(bf2f(u[1]), nw, acc.y);
            acc.z = fmaf(bf2f(u[2]), nw, acc.z);
            acc.w = fmaf(bf2f(u[3]), nw, acc.w);
        }
    }
    *(float4*)(out + (size_t)node * C_HID + c) = acc;
}

extern "C" void kernel_launch(void* const* d_in, const int* in_sizes, int n_in,
                              void* d_out, int out_size, void* d_ws, size_t ws_size,
                              hipStream_t stream) {
    const float* x = (const float*)d_in[0];
    const int* ei = (const int*)d_in[1];
    const float* W1 = (const float*)d_in[2];
    const float* b1 = (const float*)d_in[3];
    const float* W2 = (const float*)d_in[4];
    const float* b2 = (const float*)d_in[5];
    float* out = (float*)d_out;

    const int* src = ei;
    const int* dst = ei + NE;

    // workspace layout (4-byte units)
    int* cnt = (int*)d_ws;                       // 50048
    int* rowptr = cnt + 50048;                   // 50064 (NN+1)
    int* cursor = rowptr + 50064;                // 50048
    float* dinv = (float*)(cursor + 50048);      // 50048
    int* bsum = (int*)(dinv + 50048);            // 256
    int* bpre = bsum + 256;                      // 256
    ushort* Wt1 = (ushort*)(bpre + 256);         // 384*128*2 = 98304 shorts (frag-linear hi+lo)
    ushort* Wt2 = Wt1 + 98304;                   // 128*128*2 = 32768 shorts
    int2* csr = (int2*)(Wt2 + 32768);            // NE int2 = 1600000 ints
    ushort* A_bf = (ushort*)(csr + NE);          // NN*128 shorts (h bf16)
    float* B = (float*)(A_bf + (size_t)NN * C_HID);  // NN*128 fp32 (agg buffer)

    hipMemsetAsync(cnt, 0, NN * sizeof(int), stream);
    k_wconv<<<(C_IN * C_HID + 255) / 256, 256, 0, stream>>>(W1, Wt1, C_IN);
    k_wconv<<<(C_HID * C_HID + 255) / 256, 256, 0, stream>>>(W2, Wt2, C_HID);
    k_deg<<<(NE + 255) / 256, 256, 0, stream>>>(dst, cnt);
    k_dinv<<<NB, 256, 0, stream>>>(cnt, dinv);
    k_bsum<<<NB, 256, 0, stream>>>(cnt, bsum);
    k_sbs<<<1, 256, 0, stream>>>(bsum, bpre);
    k_write<<<NB, 256, 0, stream>>>(cnt, bpre, rowptr, cursor);
    k_fill<<<(NE + 255) / 256, 256, 0, stream>>>(src, dst, dinv, cursor, csr);

    const int gblocks = (NN + 63) / 64;
    const int agblocks = (NN + 7) / 8;
    // layer 1: h1 = x@W1 -> A_bf (bf16) ;  B = h1*dinv^2 (fp32 self-loop init)
    k_gemm_mfma<false, false><<<gblocks, 256, 0, stream>>>(x, Wt1, nullptr, nullptr, dinv, A_bf, B, C_IN);
    // B += gather(h1)
    k_gather<<<agblocks, 256, 0, stream>>>(A_bf, rowptr, csr, dinv, B);
    // layer 2: h2 = relu(B + b1)@W2 -> A_bf ; out = h2*dinv^2 + b2 (self-loop init)
    k_gemm_mfma<true, true><<<gblocks, 256, 0, stream>>>(B, Wt2, b1, b2, dinv, A_bf, out, C_HID);
    // out += gather(h2)
    k_gather<<<agblocks, 256, 0, stream>>>(A_bf, rowptr, csr, dinv, out);
}